// Round 1
// baseline (1386.088 us; speedup 1.0000x reference)
//
#include <hip/hip_runtime.h>
#include <hip/hip_bf16.h>

// SymGAT fused layer, fp32 correctness-first implementation.
// Algebraic folding: z, z_e never materialized.
//   c_s1 = W_fc  @ a_attn[0:128]    (zs1 = h . c_s1)
//   c_s2 = W_fce @ a_attn[128:256]  (zs2 = e_ji . c_s2)
//   c_s3 = W_fc  @ a_attn[256:384]
//   c_e1 = W_fc  @ a_attn_e[0:128], c_e2 = W_fce @ a_attn_e[128:256], c_e3 = W_fc @ a_attn_e[256:384]
//   Mc[0:128]   = W_fc  @ W_mix[0:128]
//   Mc[128:256] = W_fce @ W_mix[128:256]
//   h_f + h_r = (aggh_f+aggh_r) @ Mc_top + (agge_f+agge_r) @ Mc_bot + 2*b_mix

__device__ inline float lrelu(float x) { return x > 0.f ? x : 0.01f * x; }

// ---------------- K0: weight combos ----------------
__global__ void k_combine(const float* __restrict__ Wfc, const float* __restrict__ Wfce,
                          const float* __restrict__ Wmix, const float* __restrict__ aat,
                          const float* __restrict__ aate, float* __restrict__ Mc,
                          float* __restrict__ cvec) {
  int b = blockIdx.x, j = threadIdx.x;
  if (b < 256) {
    const float* Arow;
    const float* Wm;
    if (b < 128) { Arow = Wfc + b * 128; Wm = Wmix; }
    else         { Arow = Wfce + (b - 128) * 128; Wm = Wmix + 128 * 128; }
    float acc = 0.f;
    for (int t = 0; t < 128; ++t) acc += Arow[t] * Wm[t * 128 + j];
    Mc[b * 128 + j] = acc;
  } else {
    int idx = b - 256;
    const float* W; const float* a;
    switch (idx) {
      case 0: W = Wfc;  a = aat;        break;  // c_s1
      case 1: W = Wfce; a = aat + 128;  break;  // c_s2
      case 2: W = Wfc;  a = aat + 256;  break;  // c_s3
      case 3: W = Wfc;  a = aate;       break;  // c_e1
      case 4: W = Wfce; a = aate + 128; break;  // c_e2
      default: W = Wfc; a = aate + 256; break;  // c_e3
    }
    float acc = 0.f;
    for (int t = 0; t < 128; ++t) acc += W[j * 128 + t] * a[t];
    cvec[idx * 128 + j] = acc;
  }
}

// ---------------- generic fp32 GEMM: out[M][128] = A[M][KD] @ W[KD][128] + bias*bscale ----------------
template <int KD>
__global__ __launch_bounds__(256) void k_gemm_bias(const float* __restrict__ A,
                                                   const float* __restrict__ W,
                                                   const float* __restrict__ bias, float bscale,
                                                   float* __restrict__ outp, int M) {
  __shared__ float Als[64][132];
  int tid = threadIdx.x;
  int cg = tid & 31, rg = tid >> 5;
  long mbase = (long)blockIdx.x * 64;
  float acc[8][4] = {};
  for (int kc = 0; kc < KD; kc += 128) {
    __syncthreads();
#pragma unroll
    for (int it = 0; it < 8; ++it) {
      int idx = tid + it * 256;
      int r = idx >> 5, cv = idx & 31;
      long m = mbase + r;
      float4 v = make_float4(0.f, 0.f, 0.f, 0.f);
      if (m < M) v = *(const float4*)&A[m * KD + kc + 4 * cv];
      *(float4*)&Als[r][4 * cv] = v;
    }
    __syncthreads();
    for (int k = 0; k < 128; ++k) {
      float4 w = *(const float4*)&W[(kc + k) * 128 + 4 * cg];
#pragma unroll
      for (int rr = 0; rr < 8; ++rr) {
        float a = Als[rg * 8 + rr][k];
        acc[rr][0] += a * w.x; acc[rr][1] += a * w.y;
        acc[rr][2] += a * w.z; acc[rr][3] += a * w.w;
      }
    }
  }
  float4 bb = *(const float4*)&bias[4 * cg];
#pragma unroll
  for (int rr = 0; rr < 8; ++rr) {
    long m = mbase + rg * 8 + rr;
    if (m < M) {
      float4 o;
      o.x = acc[rr][0] + bb.x * bscale; o.y = acc[rr][1] + bb.y * bscale;
      o.z = acc[rr][2] + bb.z * bscale; o.w = acc[rr][3] + bb.w * bscale;
      *(float4*)&outp[m * 128 + 4 * cg] = o;
    }
  }
}

// ---------------- K2: fused edge kernel ----------------
// e_ji = relu(e@W_B3 + b_B3 + B1h[src] + B2h[dst]) + e ; zs2 = e_ji.c_s2 ; ze2 = e_ji.c_e2
__global__ __launch_bounds__(256) void k_edge(const float* __restrict__ e,
                                              const float* __restrict__ W,
                                              const float* __restrict__ bias,
                                              const float* __restrict__ B1h,
                                              const float* __restrict__ B2h,
                                              const int* __restrict__ src, const int* __restrict__ dst,
                                              const float* __restrict__ cs2, const float* __restrict__ ce2,
                                              float* __restrict__ eout, float* __restrict__ zs2,
                                              float* __restrict__ ze2, int M) {
  __shared__ float Als[64][132];
  int tid = threadIdx.x;
  int cg = tid & 31, rg = tid >> 5;
  long mbase = (long)blockIdx.x * 64;
#pragma unroll
  for (int it = 0; it < 8; ++it) {
    int idx = tid + it * 256;
    int r = idx >> 5, cv = idx & 31;
    long m = mbase + r;
    float4 v = make_float4(0.f, 0.f, 0.f, 0.f);
    if (m < M) v = *(const float4*)&e[m * 128 + 4 * cv];
    *(float4*)&Als[r][4 * cv] = v;
  }
  __syncthreads();
  float acc[8][4] = {};
  for (int k = 0; k < 128; ++k) {
    float4 w = *(const float4*)&W[k * 128 + 4 * cg];
#pragma unroll
    for (int rr = 0; rr < 8; ++rr) {
      float a = Als[rg * 8 + rr][k];
      acc[rr][0] += a * w.x; acc[rr][1] += a * w.y;
      acc[rr][2] += a * w.z; acc[rr][3] += a * w.w;
    }
  }
  float4 bb = *(const float4*)&bias[4 * cg];
  float4 c2s = *(const float4*)&cs2[4 * cg];
  float4 c2e = *(const float4*)&ce2[4 * cg];
#pragma unroll
  for (int rr = 0; rr < 8; ++rr) {
    int rl = rg * 8 + rr;
    long m = mbase + rl;
    bool valid = (m < M);
    float ps = 0.f, pe = 0.f;
    float o0 = 0.f, o1 = 0.f, o2 = 0.f, o3 = 0.f;
    if (valid) {
      int s = src[m], dv = dst[m];
      float4 b1 = *(const float4*)&B1h[(long)s * 128 + 4 * cg];
      float4 b2 = *(const float4*)&B2h[(long)dv * 128 + 4 * cg];
      o0 = fmaxf(acc[rr][0] + bb.x + b1.x + b2.x, 0.f) + Als[rl][4 * cg + 0];
      o1 = fmaxf(acc[rr][1] + bb.y + b1.y + b2.y, 0.f) + Als[rl][4 * cg + 1];
      o2 = fmaxf(acc[rr][2] + bb.z + b1.z + b2.z, 0.f) + Als[rl][4 * cg + 2];
      o3 = fmaxf(acc[rr][3] + bb.w + b1.w + b2.w, 0.f) + Als[rl][4 * cg + 3];
      *(float4*)&eout[m * 128 + 4 * cg] = make_float4(o0, o1, o2, o3);
      ps = o0 * c2s.x + o1 * c2s.y + o2 * c2s.z + o3 * c2s.w;
      pe = o0 * c2e.x + o1 * c2e.y + o2 * c2e.z + o3 * c2e.w;
    }
#pragma unroll
    for (int mk = 1; mk < 32; mk <<= 1) {
      ps += __shfl_xor(ps, mk);
      pe += __shfl_xor(pe, mk);
    }
    if (valid && cg == 0) { zs2[m] = ps; ze2[m] = pe; }
  }
}

// ---------------- K3: node matvecs ----------------
__global__ void k_nodevec(const float* __restrict__ h, const float* __restrict__ cvec,
                          float* __restrict__ zs1, float* __restrict__ zs3,
                          float* __restrict__ ze1, float* __restrict__ ze3, int n) {
  int wave = threadIdx.x >> 6, lane = threadIdx.x & 63;
  long i = (long)blockIdx.x * 4 + wave;
  if (i >= n) return;
  float2 hv = *(const float2*)&h[i * 128 + 2 * lane];
  const float* c1 = cvec;            // c_s1
  const float* c3 = cvec + 256;      // c_s3
  const float* e1 = cvec + 384;      // c_e1
  const float* e3 = cvec + 640;      // c_e3
  float p1 = hv.x * c1[2 * lane] + hv.y * c1[2 * lane + 1];
  float p3 = hv.x * c3[2 * lane] + hv.y * c3[2 * lane + 1];
  float q1 = hv.x * e1[2 * lane] + hv.y * e1[2 * lane + 1];
  float q3 = hv.x * e3[2 * lane] + hv.y * e3[2 * lane + 1];
#pragma unroll
  for (int mk = 1; mk < 64; mk <<= 1) {
    p1 += __shfl_xor(p1, mk); p3 += __shfl_xor(p3, mk);
    q1 += __shfl_xor(q1, mk); q3 += __shfl_xor(q3, mk);
  }
  if (lane == 0) { zs1[i] = p1; zs3[i] = p3; ze1[i] = q1; ze3[i] = q3; }
}

// ---------------- CSR build ----------------
__global__ void k_hist(const int* __restrict__ src, const int* __restrict__ dst,
                       int* __restrict__ cntf, int* __restrict__ cntr, int E) {
  int e = blockIdx.x * 256 + threadIdx.x;
  if (e < E) {
    atomicAdd(&cntf[dst[e]], 1);
    atomicAdd(&cntr[src[e]], 1);
  }
}

__global__ __launch_bounds__(1024) void k_scan(const int* __restrict__ cntf,
                                               const int* __restrict__ cntr,
                                               int* __restrict__ offf, int* __restrict__ offr, int n) {
  __shared__ int part[1024];
  int tid = threadIdx.x;
  for (int pass = 0; pass < 2; ++pass) {
    const int* cnt = pass ? cntr : cntf;
    int* off = pass ? offr : offf;
    int per = (n + 1023) >> 10;
    int beg = tid * per; if (beg > n) beg = n;
    int end = beg + per; if (end > n) end = n;
    int s = 0;
    for (int i = beg; i < end; ++i) s += cnt[i];
    part[tid] = s;
    __syncthreads();
    for (int o = 1; o < 1024; o <<= 1) {
      int vv = (tid >= o) ? part[tid - o] : 0;
      __syncthreads();
      part[tid] += vv;
      __syncthreads();
    }
    int run = tid ? part[tid - 1] : 0;
    for (int i = beg; i < end; ++i) { off[i] = run; run += cnt[i]; }
    if (tid == 1023) off[n] = part[1023];
    __syncthreads();
  }
}

__global__ void k_fill(const int* __restrict__ src, const int* __restrict__ dst,
                       const int* __restrict__ offf, const int* __restrict__ offr,
                       int* __restrict__ curf, int* __restrict__ curr,
                       int* __restrict__ eidf, int* __restrict__ eidr, int E) {
  int e = blockIdx.x * 256 + threadIdx.x;
  if (e >= E) return;
  int d = dst[e];
  int p = atomicAdd(&curf[d], 1);
  eidf[offf[d] + p] = e;
  int s = src[e];
  p = atomicAdd(&curr[s], 1);
  eidr[offr[s] + p] = e;
}

// ---------------- K5: scores in sorted order ----------------
__global__ void k_scores(const int* __restrict__ src, const int* __restrict__ dst,
                         const int* __restrict__ eidf, const int* __restrict__ eidr,
                         const float* __restrict__ zs1, const float* __restrict__ zs2,
                         const float* __restrict__ zs3, const float* __restrict__ ze1,
                         const float* __restrict__ ze2, const float* __restrict__ ze3,
                         float* __restrict__ sf, float* __restrict__ sef,
                         float* __restrict__ sr, float* __restrict__ ser, int E) {
  int p = blockIdx.x * 256 + threadIdx.x;
  if (p >= E) return;
  {
    int e = eidf[p];
    int s = src[e], d = dst[e];
    float z2 = zs2[e], ze2v = ze2[e];
    sf[p] = lrelu(zs1[s] + z2 + zs3[d]);
    sef[p] = lrelu(ze1[s] + ze2v + ze3[d]);
  }
  {
    int e = eidr[p];
    int s = src[e], d = dst[e];
    float z2 = zs2[e], ze2v = ze2[e];
    sr[p] = lrelu(zs1[d] + z2 + zs3[s]);
    ser[p] = lrelu(ze1[d] + ze2v + ze3[s]);
  }
}

// ---------------- K6: per-node softmax + aggregate (both directions) ----------------
__device__ inline float wred_max(float v) {
#pragma unroll
  for (int mk = 32; mk; mk >>= 1) v = fmaxf(v, __shfl_xor(v, mk));
  return v;
}
__device__ inline float wred_sum(float v) {
#pragma unroll
  for (int mk = 32; mk; mk >>= 1) v += __shfl_xor(v, mk);
  return v;
}

__global__ __launch_bounds__(128) void k_agg(const int* __restrict__ offf, const int* __restrict__ eidf,
                                             const int* __restrict__ offr, const int* __restrict__ eidr,
                                             const int* __restrict__ src, const int* __restrict__ dst,
                                             const float* __restrict__ sf, const float* __restrict__ sef,
                                             const float* __restrict__ sr, const float* __restrict__ ser,
                                             const float* __restrict__ h, const float* __restrict__ ej,
                                             float* __restrict__ agg, int n) {
  __shared__ float red[4];
  int v = blockIdx.x;
  int tid = threadIdx.x;
  int wid = tid >> 6;
  float acch = 0.f, acce = 0.f;
  for (int dir = 0; dir < 2; ++dir) {
    const int* off = dir ? offr : offf;
    const int* eid = dir ? eidr : eidf;
    const float* sc = dir ? sr : sf;
    const float* sce = dir ? ser : sef;
    const int* nbr = dir ? dst : src;
    int s0 = off[v], s1 = off[v + 1];
    if (s1 > s0) {
      float m1 = -1e30f, m2 = -1e30f;
      for (int i = s0 + tid; i < s1; i += 128) {
        m1 = fmaxf(m1, sc[i]);
        m2 = fmaxf(m2, sce[i]);
      }
      m1 = wred_max(m1); m2 = wred_max(m2);
      if ((tid & 63) == 0) { red[wid * 2] = m1; red[wid * 2 + 1] = m2; }
      __syncthreads();
      m1 = fmaxf(red[0], red[2]); m2 = fmaxf(red[1], red[3]);
      __syncthreads();
      float d1 = 0.f, d2 = 0.f;
      for (int i = s0 + tid; i < s1; i += 128) {
        d1 += __expf(sc[i] - m1);
        d2 += __expf(sce[i] - m2);
      }
      d1 = wred_sum(d1); d2 = wred_sum(d2);
      if ((tid & 63) == 0) { red[wid * 2] = d1; red[wid * 2 + 1] = d2; }
      __syncthreads();
      d1 = red[0] + red[2]; d2 = red[1] + red[3];
      __syncthreads();
      float i1 = 1.f / d1, i2 = 1.f / d2;
      for (int i = s0; i < s1; ++i) {
        int e = eid[i];
        int nb = nbr[e];
        float w1 = __expf(sc[i] - m1) * i1;
        float w2 = __expf(sce[i] - m2) * i2;
        acch += w1 * h[(long)nb * 128 + tid];
        acce += w2 * ej[(long)e * 128 + tid];
      }
    }
  }
  agg[(long)v * 256 + tid] = acch;
  agg[(long)v * 256 + 128 + tid] = acce;
}

// ---------------- K8: LayerNorm + relu + residual ----------------
__global__ void k_ln(const float* __restrict__ pre, const float* __restrict__ h,
                     const float* __restrict__ g, const float* __restrict__ b,
                     float* __restrict__ outp, int n) {
  int wave = threadIdx.x >> 6, lane = threadIdx.x & 63;
  long i = (long)blockIdx.x * 4 + wave;
  if (i >= n) return;
  float2 x = *(const float2*)&pre[i * 128 + 2 * lane];
  float s = x.x + x.y;
#pragma unroll
  for (int mk = 1; mk < 64; mk <<= 1) s += __shfl_xor(s, mk);
  float mu = s * (1.f / 128.f);
  float dx = x.x - mu, dy = x.y - mu;
  float q = dx * dx + dy * dy;
#pragma unroll
  for (int mk = 1; mk < 64; mk <<= 1) q += __shfl_xor(q, mk);
  float var = q * (1.f / 128.f);
  float rstd = rsqrtf(var + 1e-5f);
  float2 hv = *(const float2*)&h[i * 128 + 2 * lane];
  float g0 = g[2 * lane], g1 = g[2 * lane + 1];
  float b0 = b[2 * lane], b1 = b[2 * lane + 1];
  float o0 = fmaxf(dx * rstd * g0 + b0, 0.f) + hv.x;
  float o1 = fmaxf(dy * rstd * g1 + b1, 0.f) + hv.y;
  *(float2*)&outp[i * 128 + 2 * lane] = make_float2(o0, o1);
}

extern "C" void kernel_launch(void* const* d_in, const int* in_sizes, int n_in,
                              void* d_out, int out_size, void* d_ws, size_t ws_size,
                              hipStream_t stream) {
  const float* h = (const float*)d_in[0];
  const float* e = (const float*)d_in[1];
  const int* src = (const int*)d_in[2];
  const int* dst = (const int*)d_in[3];
  const float* Wfc = (const float*)d_in[4];
  const float* Wfce = (const float*)d_in[5];
  const float* aat = (const float*)d_in[6];
  const float* aate = (const float*)d_in[7];
  const float* WB1 = (const float*)d_in[8];
  const float* bB1 = (const float*)d_in[9];
  const float* WB2 = (const float*)d_in[10];
  const float* bB2 = (const float*)d_in[11];
  const float* WB3 = (const float*)d_in[12];
  const float* bB3 = (const float*)d_in[13];
  const float* Wmix = (const float*)d_in[14];
  const float* bmix = (const float*)d_in[15];
  const float* lng = (const float*)d_in[16];
  const float* lnb = (const float*)d_in[17];
  int n = in_sizes[0] / 128;
  int E = in_sizes[1] / 128;

  float* hout = (float*)d_out;
  float* eout = (float*)d_out + (size_t)n * 128;

  char* w = (char*)d_ws;
  auto alloc = [&](size_t bytes) {
    void* p = w;
    w += (bytes + 255) / 256 * 256;
    return p;
  };
  float* B1h = (float*)alloc((size_t)n * 128 * 4);
  float* B2h = (float*)alloc((size_t)n * 128 * 4);
  float* agg = (float*)alloc((size_t)n * 256 * 4);
  float* pre = (float*)alloc((size_t)n * 128 * 4);
  float* zs1 = (float*)alloc((size_t)n * 4);
  float* zs3 = (float*)alloc((size_t)n * 4);
  float* ze1 = (float*)alloc((size_t)n * 4);
  float* ze3 = (float*)alloc((size_t)n * 4);
  float* zs2 = (float*)alloc((size_t)E * 4);
  float* ze2 = (float*)alloc((size_t)E * 4);
  float* sf = (float*)alloc((size_t)E * 4);
  float* sef = (float*)alloc((size_t)E * 4);
  float* sr = (float*)alloc((size_t)E * 4);
  float* ser = (float*)alloc((size_t)E * 4);
  float* Mc = (float*)alloc(256 * 128 * 4);
  float* cvec = (float*)alloc(768 * 4);
  int* offf = (int*)alloc((size_t)(n + 1) * 4);
  int* offr = (int*)alloc((size_t)(n + 1) * 4);
  int* curf = (int*)alloc((size_t)n * 4);
  int* curr = (int*)alloc((size_t)n * 4);
  int* eidf = (int*)alloc((size_t)E * 4);
  int* eidr = (int*)alloc((size_t)E * 4);

  hipMemsetAsync(curf, 0, (size_t)n * 4, stream);
  hipMemsetAsync(curr, 0, (size_t)n * 4, stream);

  k_combine<<<262, 128, 0, stream>>>(Wfc, Wfce, Wmix, aat, aate, Mc, cvec);
  k_gemm_bias<128><<<(n + 63) / 64, 256, 0, stream>>>(h, WB1, bB1, 1.f, B1h, n);
  k_gemm_bias<128><<<(n + 63) / 64, 256, 0, stream>>>(h, WB2, bB2, 1.f, B2h, n);
  k_hist<<<(E + 255) / 256, 256, 0, stream>>>(src, dst, curf, curr, E);
  k_scan<<<1, 1024, 0, stream>>>(curf, curr, offf, offr, n);
  hipMemsetAsync(curf, 0, (size_t)n * 4, stream);
  hipMemsetAsync(curr, 0, (size_t)n * 4, stream);
  k_fill<<<(E + 255) / 256, 256, 0, stream>>>(src, dst, offf, offr, curf, curr, eidf, eidr, E);
  k_edge<<<(E + 63) / 64, 256, 0, stream>>>(e, WB3, bB3, B1h, B2h, src, dst, cvec + 128, cvec + 512,
                                            eout, zs2, ze2, E);
  k_nodevec<<<(n + 3) / 4, 256, 0, stream>>>(h, cvec, zs1, zs3, ze1, ze3, n);
  k_scores<<<(E + 255) / 256, 256, 0, stream>>>(src, dst, eidf, eidr, zs1, zs2, zs3, ze1, ze2, ze3,
                                                sf, sef, sr, ser, E);
  k_agg<<<n, 128, 0, stream>>>(offf, eidf, offr, eidr, src, dst, sf, sef, sr, ser, h, eout, agg, n);
  k_gemm_bias<256><<<(n + 63) / 64, 256, 0, stream>>>(agg, Mc, bmix, 2.f, pre, n);
  k_ln<<<(n + 3) / 4, 256, 0, stream>>>(pre, h, lng, lnb, hout, n);
}